// Round 3
// baseline (566.057 us; speedup 1.0000x reference)
//
#include <hip/hip_runtime.h>

// VentralModel: log-polar Gaussian pooling over steerable-pyramid moduli.
// Inputs (dict order): image(512*512), pyr0(4,512,512,2), win0(300,512,512),
//                      pyr1(4,256,256,2), win1(300,256,256),
//                      pyr2(4,128,128,2), win2(300,128,128),
//                      pyr3(4,64,64,2),   win3(300,64,64)
// Output: 4 scales x (4 ori x 300 win) + 300 mean_lum = 5100 fp32.
//
// HBM-bound on streaming ~420 MB of windows. R3 changes vs R2 (160-180 us):
//  - PPT=4 lane-contiguous layout: each window load = one fully coalesced
//    1 KB/wave float4 (lane i at base + i*16B). Grid 510 -> 1020 blocks
//    (4 blocks/CU, 16 waves/CU) for latency hiding.
//  - depth-2 software prefetch of window vectors + nontemporal loads
//    (windows are stream-once; keep L2 for pyr, which is re-read per wgrp).
//  - nonzero count via __ballot/__popcll on the scalar pipe: removes ct from
//    the shuffle butterfly (36 -> 24/30 cross-lane ops per window).

#define THREADS 256
#define PPT 4                 // pixels per thread
#define CHUNK (THREADS * PPT) // 1024 pixels per block
#define WPG 100               // windows per group (3 groups x 100 = 300)
#define ZTHRESH 1e-20f

// ws float layout:
//   [0,4800)    sums[s][o][w]  (s*1200 + o*300 + w)
//   [4800,6000) cnt[s][w]      (4800 + s*300 + w)
//   [6000,6300) imgsum[w]
#define WS_FLOATS 6300

typedef float fvec4 __attribute__((ext_vector_type(4)));

template <bool HAS_IMG>
__device__ __forceinline__ void pool_scale(const float* __restrict__ pyr,
                                           const float* __restrict__ win,
                                           const float* __restrict__ img,
                                           float* __restrict__ ws,
                                           int HW, int scale, int chunk, int wgrp)
{
    __shared__ float lacc[4][WPG * 6];   // per-wave slots, no LDS atomics
    const int tid  = threadIdx.x;
    const int lane = tid & 63;
    const int wave = tid >> 6;

    const size_t pix0 = (size_t)chunk * CHUNK + (size_t)tid * PPT;

    // ---- moduli for 4 pixels x 4 orientations, kept in registers ----
    float mm[4][PPT];
#pragma unroll
    for (int o = 0; o < 4; ++o) {
        const float4* pp = (const float4*)(pyr + ((size_t)o * HW + pix0) * 2);
        float4 v0 = pp[0];
        float4 v1 = pp[1];
        mm[o][0] = sqrtf(fmaf(v0.x, v0.x, v0.y * v0.y));
        mm[o][1] = sqrtf(fmaf(v0.z, v0.z, v0.w * v0.w));
        mm[o][2] = sqrtf(fmaf(v1.x, v1.x, v1.y * v1.y));
        mm[o][3] = sqrtf(fmaf(v1.z, v1.z, v1.w * v1.w));
    }
    float4 iv = make_float4(0.f, 0.f, 0.f, 0.f);
    if (HAS_IMG) iv = *(const float4*)(img + pix0);

    const int w0 = wgrp * WPG;
    const float* wbase = win + pix0;

    // ---- stream windows, depth-2 pipelined nontemporal loads ----
    fvec4 c0 = __builtin_nontemporal_load((const fvec4*)(wbase + (size_t)(w0 + 0) * HW));
    fvec4 c1 = __builtin_nontemporal_load((const fvec4*)(wbase + (size_t)(w0 + 1) * HW));
    for (int wi = 0; wi < WPG; ++wi) {
        fvec4 cn;
        if (wi + 2 < WPG)
            cn = __builtin_nontemporal_load((const fvec4*)(wbase + (size_t)(w0 + wi + 2) * HW));
        else
            cn = (fvec4)(0.f);

        // nonzero count on the scalar pipe (wave-uniform)
        int ct = __popcll(__ballot(c0.x > ZTHRESH))
               + __popcll(__ballot(c0.y > ZTHRESH))
               + __popcll(__ballot(c0.z > ZTHRESH))
               + __popcll(__ballot(c0.w > ZTHRESH));

        float a0, a1, a2, a3, ia = 0.f;
        a0 = fmaf(c0.w, mm[0][3], fmaf(c0.z, mm[0][2], fmaf(c0.y, mm[0][1], c0.x * mm[0][0])));
        a1 = fmaf(c0.w, mm[1][3], fmaf(c0.z, mm[1][2], fmaf(c0.y, mm[1][1], c0.x * mm[1][0])));
        a2 = fmaf(c0.w, mm[2][3], fmaf(c0.z, mm[2][2], fmaf(c0.y, mm[2][1], c0.x * mm[2][0])));
        a3 = fmaf(c0.w, mm[3][3], fmaf(c0.z, mm[3][2], fmaf(c0.y, mm[3][1], c0.x * mm[3][0])));
        if (HAS_IMG)
            ia = fmaf(c0.w, iv.w, fmaf(c0.z, iv.z, fmaf(c0.y, iv.y, c0.x * iv.x)));

        // wave-64 butterfly (4 or 5 values)
#pragma unroll
        for (int s = 1; s < 64; s <<= 1) {
            a0 += __shfl_xor(a0, s, 64);
            a1 += __shfl_xor(a1, s, 64);
            a2 += __shfl_xor(a2, s, 64);
            a3 += __shfl_xor(a3, s, 64);
            if (HAS_IMG) ia += __shfl_xor(ia, s, 64);
        }
        if (lane == 0) {
            float* slot = &lacc[wave][wi * 6];
            slot[0] = a0; slot[1] = a1; slot[2] = a2; slot[3] = a3;
            slot[4] = (float)ct; slot[5] = HAS_IMG ? ia : 0.f;
        }
        c0 = c1; c1 = cn;
    }
    __syncthreads();

    // ---- block flush: sum 4 waves, one global atomicAdd per value ----
    float* sums = ws + (size_t)scale * 1200;
    float* cnt  = ws + 4800 + (size_t)scale * 300;
    float* imgs = ws + 6000;
    for (int i = tid; i < WPG * 6; i += THREADS) {
        float v = lacc[0][i] + lacc[1][i] + lacc[2][i] + lacc[3][i];
        int wi = i / 6, f = i - wi * 6;
        int w = w0 + wi;
        if (f < 4) {
            atomicAdd(&sums[f * 300 + w], v);
        } else if (f == 4) {
            atomicAdd(&cnt[w], v);
        } else if (HAS_IMG) {
            atomicAdd(&imgs[w], v);
        }
    }
}

// grid: s0: 256 chunks x 3 wgrps = 768 | s1: 64x3=192 | s2: 16x3=48 | s3: 4x3=12
// total 1020 blocks (4 blocks/CU). Blocks sharing a chunk are 256 apart ->
// same XCD under round-robin dispatch (256 % 8 == 0): pyr L2 reuse.
__global__ __launch_bounds__(THREADS)
void pool_kernel(const float* __restrict__ image,
                 const float* __restrict__ pyr0, const float* __restrict__ win0,
                 const float* __restrict__ pyr1, const float* __restrict__ win1,
                 const float* __restrict__ pyr2, const float* __restrict__ win2,
                 const float* __restrict__ pyr3, const float* __restrict__ win3,
                 float* __restrict__ ws)
{
    int bid = blockIdx.x;
    if (bid < 768) {
        int chunk = bid & 255, wgrp = bid >> 8;
        pool_scale<true>(pyr0, win0, image, ws, 512 * 512, 0, chunk, wgrp);
    } else if (bid < 960) {
        int l = bid - 768;
        int chunk = l & 63, wgrp = l >> 6;
        pool_scale<false>(pyr1, win1, nullptr, ws, 256 * 256, 1, chunk, wgrp);
    } else if (bid < 1008) {
        int l = bid - 960;
        int chunk = l & 15, wgrp = l >> 4;
        pool_scale<false>(pyr2, win2, nullptr, ws, 128 * 128, 2, chunk, wgrp);
    } else {
        int l = bid - 1008;
        int chunk = l & 3, wgrp = l >> 2;
        pool_scale<false>(pyr3, win3, nullptr, ws, 64 * 64, 3, chunk, wgrp);
    }
}

__global__ __launch_bounds__(THREADS)
void finalize_kernel(const float* __restrict__ ws, float* __restrict__ out)
{
    int i = blockIdx.x * blockDim.x + threadIdx.x;
    if (i >= 5100) return;
    float v;
    if (i < 4800) {
        int s = i / 1200;
        int w = i % 300;
        v = ws[i] / ws[4800 + s * 300 + w];        // sums[s][o][w] / cnt[s][w]
    } else {
        int w = i - 4800;
        v = ws[6000 + w] / ws[4800 + w];           // imgsum[w] / cnt[0][w]
    }
    out[i] = v;
}

extern "C" void kernel_launch(void* const* d_in, const int* in_sizes, int n_in,
                              void* d_out, int out_size, void* d_ws, size_t ws_size,
                              hipStream_t stream)
{
    const float* image = (const float*)d_in[0];
    const float* pyr0  = (const float*)d_in[1];
    const float* win0  = (const float*)d_in[2];
    const float* pyr1  = (const float*)d_in[3];
    const float* win1  = (const float*)d_in[4];
    const float* pyr2  = (const float*)d_in[5];
    const float* win2  = (const float*)d_in[6];
    const float* pyr3  = (const float*)d_in[7];
    const float* win3  = (const float*)d_in[8];
    float* ws  = (float*)d_ws;
    float* out = (float*)d_out;

    hipMemsetAsync(d_ws, 0, WS_FLOATS * sizeof(float), stream);
    pool_kernel<<<1020, THREADS, 0, stream>>>(image, pyr0, win0, pyr1, win1,
                                              pyr2, win2, pyr3, win3, ws);
    finalize_kernel<<<(5100 + THREADS - 1) / THREADS, THREADS, 0, stream>>>(ws, out);
}

// Round 5
// 505.512 us; speedup vs baseline: 1.1198x; 1.1198x over previous
//
#include <hip/hip_runtime.h>

// VentralModel: log-polar Gaussian pooling over steerable-pyramid moduli.
// Output: 4 scales x (4 ori x 300 win) + 300 mean_lum = 5100 fp32.
//
// HBM-bound on streaming ~420 MB of windows.
// R5 = R4 with the shuffle-divergence bug fixed:
//  - R4 put __shfl_xor inside ternary arms; under divergent codegen the
//    xor-partner lane is exec-masked off and ds_bpermute reads undefined
//    data -> NaN. R5 hoists ALL shuffles into unconditional statements and
//    selects on the shuffled results only (same 14-shuffle folded tree,
//    same pairwise-summation numerics as the R2 butterfly).
//  - PPT=8 as two lane-contiguous float4 halves (fully coalesced 1 KB wave
//    loads), depth-2 nontemporal prefetch, count folded into the tree.
//  - LDS-pipe demand per 16 KB memory round: 8 waves x 14 x ~6 cyc ~= 700 cyc
//    << 1600 cyc HBM -> memory-bound.

#define THREADS 256
#define PPT 8                 // pixels per thread (two float4 halves)
#define CHUNK (THREADS * PPT) // 2048 pixels per block
#define HALFPX 1024           // pixels per half-chunk
#define WPG 100               // windows per group (3 groups x 100 = 300)
#define ZTHRESH 1e-20f

// ws float layout:
//   [0,4800)    sums[s][o][w]  (s*1200 + o*300 + w)
//   [4800,6000) cnt[s][w]      (4800 + s*300 + w)
//   [6000,6300) imgsum[w]
#define WS_FLOATS 6300

typedef float fvec4 __attribute__((ext_vector_type(4)));

template <bool HAS_IMG>
__device__ __forceinline__ void pool_scale(const float* __restrict__ pyr,
                                           const float* __restrict__ win,
                                           const float* __restrict__ img,
                                           float* __restrict__ ws,
                                           int HW, int scale, int chunk, int wgrp)
{
    __shared__ float lacc[4][WPG * 6];
    const int tid  = threadIdx.x;
    const int lane = tid & 63;
    const int wave = tid >> 6;

    // two lane-contiguous 4-pixel halves per thread
    const size_t p0 = (size_t)chunk * CHUNK + (size_t)tid * 4;
    const size_t p1 = p0 + HALFPX;

    // ---- moduli: m0[o][j] for half0 pixels, m1[o][j] for half1 ----
    float m0[4][4], m1[4][4];
#pragma unroll
    for (int o = 0; o < 4; ++o) {
        const float4* pa = (const float4*)(pyr + ((size_t)o * HW + p0) * 2);
        float4 v0 = pa[0], v1 = pa[1];
        m0[o][0] = sqrtf(fmaf(v0.x, v0.x, v0.y * v0.y));
        m0[o][1] = sqrtf(fmaf(v0.z, v0.z, v0.w * v0.w));
        m0[o][2] = sqrtf(fmaf(v1.x, v1.x, v1.y * v1.y));
        m0[o][3] = sqrtf(fmaf(v1.z, v1.z, v1.w * v1.w));
        const float4* pb = (const float4*)(pyr + ((size_t)o * HW + p1) * 2);
        float4 w0v = pb[0], w1v = pb[1];
        m1[o][0] = sqrtf(fmaf(w0v.x, w0v.x, w0v.y * w0v.y));
        m1[o][1] = sqrtf(fmaf(w0v.z, w0v.z, w0v.w * w0v.w));
        m1[o][2] = sqrtf(fmaf(w1v.x, w1v.x, w1v.y * w1v.y));
        m1[o][3] = sqrtf(fmaf(w1v.z, w1v.z, w1v.w * w1v.w));
    }
    fvec4 i0 = (fvec4)(0.f), i1 = (fvec4)(0.f);
    if (HAS_IMG) {
        i0 = *(const fvec4*)(img + p0);
        i1 = *(const fvec4*)(img + p1);
    }

    const int w0 = wgrp * WPG;

    // ---- stream windows, depth-2 pipelined nontemporal loads ----
    fvec4 x0 = __builtin_nontemporal_load((const fvec4*)(win + (size_t)(w0 + 0) * HW + p0));
    fvec4 y0 = __builtin_nontemporal_load((const fvec4*)(win + (size_t)(w0 + 0) * HW + p1));
    fvec4 x1 = __builtin_nontemporal_load((const fvec4*)(win + (size_t)(w0 + 1) * HW + p0));
    fvec4 y1 = __builtin_nontemporal_load((const fvec4*)(win + (size_t)(w0 + 1) * HW + p1));

    const bool pb0 = (lane & 1) != 0;
    const bool pb1 = (lane & 2) != 0;
    const bool pb2 = (lane & 4) != 0;

    for (int wi = 0; wi < WPG; ++wi) {
        fvec4 xn = (fvec4)(0.f), yn = (fvec4)(0.f);
        if (wi + 2 < WPG) {
            const float* r = win + (size_t)(w0 + wi + 2) * HW;
            xn = __builtin_nontemporal_load((const fvec4*)(r + p0));
            yn = __builtin_nontemporal_load((const fvec4*)(r + p1));
        }

        float a0 = 0.f, a1 = 0.f, a2 = 0.f, a3 = 0.f, ct = 0.f, ia = 0.f;
#pragma unroll
        for (int j = 0; j < 4; ++j) {
            float wx = x0[j], wy = y0[j];
            a0 = fmaf(wy, m1[0][j], fmaf(wx, m0[0][j], a0));
            a1 = fmaf(wy, m1[1][j], fmaf(wx, m0[1][j], a1));
            a2 = fmaf(wy, m1[2][j], fmaf(wx, m0[2][j], a2));
            a3 = fmaf(wy, m1[3][j], fmaf(wx, m0[3][j], a3));
            ct += (wx > ZTHRESH) ? 1.f : 0.f;
            ct += (wy > ZTHRESH) ? 1.f : 0.f;
            if (HAS_IMG) ia = fmaf(wy, i1[j], fmaf(wx, i0[j], ia));
        }

        // ---- folded wave-64 reduction: 14 shuffles, lane r<6 gets sum r ----
        // ALL shuffles unconditional; parity selects operate on results only.
        // stage 1 (xor 1): 6 values -> 3
        float t0 = __shfl_xor(a0, 1, 64);
        float t1 = __shfl_xor(a1, 1, 64);
        float t2 = __shfl_xor(a2, 1, 64);
        float t3 = __shfl_xor(a3, 1, 64);
        float t4 = __shfl_xor(ct, 1, 64);
        float t5 = __shfl_xor(ia, 1, 64);
        float b0 = pb0 ? (a1 + t1) : (a0 + t0);
        float b1 = pb0 ? (a3 + t3) : (a2 + t2);
        float b2 = pb0 ? (ia + t5) : (ct + t4);
        // stage 2 (xor 2): 3 -> 2
        float u0 = __shfl_xor(b0, 2, 64);
        float u1 = __shfl_xor(b1, 2, 64);
        float u2 = __shfl_xor(b2, 2, 64);
        float c0 = pb1 ? (b1 + u1) : (b0 + u0);
        float c1 = b2 + u2;
        // stage 3 (xor 4): 2 -> 1
        float v0 = __shfl_xor(c0, 4, 64);
        float v1 = __shfl_xor(c1, 4, 64);
        float d  = pb2 ? (c1 + v1) : (c0 + v0);
        // stages 4-6: plain butterfly on the single value
        d += __shfl_xor(d, 8, 64);
        d += __shfl_xor(d, 16, 64);
        d += __shfl_xor(d, 32, 64);
        // lane r holds sum of value r: 0..3 -> a0..a3, 4 -> ct, 5 -> ia
        if (lane < 6) lacc[wave][wi * 6 + lane] = d;

        x0 = x1; y0 = y1; x1 = xn; y1 = yn;
    }
    __syncthreads();

    // ---- block flush: sum 4 waves, one global atomicAdd per value ----
    float* sums = ws + (size_t)scale * 1200;
    float* cnt  = ws + 4800 + (size_t)scale * 300;
    float* imgs = ws + 6000;
    for (int i = tid; i < WPG * 6; i += THREADS) {
        float v = lacc[0][i] + lacc[1][i] + lacc[2][i] + lacc[3][i];
        int wi = i / 6, f = i - wi * 6;
        int w = w0 + wi;
        if (f < 4) {
            atomicAdd(&sums[f * 300 + w], v);
        } else if (f == 4) {
            atomicAdd(&cnt[w], v);
        } else if (HAS_IMG) {
            atomicAdd(&imgs[w], v);
        }
    }
}

// grid: s0: 128 chunks x 3 wgrps = 384 | s1: 32x3=96 | s2: 8x3=24 | s3: 2x3=6
// total 510 blocks (2 blocks/CU, 8 waves/CU), each streams 100 x 8 KB.
__global__ __launch_bounds__(THREADS)
void pool_kernel(const float* __restrict__ image,
                 const float* __restrict__ pyr0, const float* __restrict__ win0,
                 const float* __restrict__ pyr1, const float* __restrict__ win1,
                 const float* __restrict__ pyr2, const float* __restrict__ win2,
                 const float* __restrict__ pyr3, const float* __restrict__ win3,
                 float* __restrict__ ws)
{
    int bid = blockIdx.x;
    if (bid < 384) {
        int chunk = bid & 127, wgrp = bid >> 7;
        pool_scale<true>(pyr0, win0, image, ws, 512 * 512, 0, chunk, wgrp);
    } else if (bid < 480) {
        int l = bid - 384;
        int chunk = l & 31, wgrp = l >> 5;
        pool_scale<false>(pyr1, win1, nullptr, ws, 256 * 256, 1, chunk, wgrp);
    } else if (bid < 504) {
        int l = bid - 480;
        int chunk = l & 7, wgrp = l >> 3;
        pool_scale<false>(pyr2, win2, nullptr, ws, 128 * 128, 2, chunk, wgrp);
    } else {
        int l = bid - 504;
        int chunk = l & 1, wgrp = l >> 1;
        pool_scale<false>(pyr3, win3, nullptr, ws, 64 * 64, 3, chunk, wgrp);
    }
}

__global__ __launch_bounds__(THREADS)
void finalize_kernel(const float* __restrict__ ws, float* __restrict__ out)
{
    int i = blockIdx.x * blockDim.x + threadIdx.x;
    if (i >= 5100) return;
    float v;
    if (i < 4800) {
        int s = i / 1200;
        int w = i % 300;
        v = ws[i] / ws[4800 + s * 300 + w];        // sums[s][o][w] / cnt[s][w]
    } else {
        int w = i - 4800;
        v = ws[6000 + w] / ws[4800 + w];           // imgsum[w] / cnt[0][w]
    }
    out[i] = v;
}

extern "C" void kernel_launch(void* const* d_in, const int* in_sizes, int n_in,
                              void* d_out, int out_size, void* d_ws, size_t ws_size,
                              hipStream_t stream)
{
    const float* image = (const float*)d_in[0];
    const float* pyr0  = (const float*)d_in[1];
    const float* win0  = (const float*)d_in[2];
    const float* pyr1  = (const float*)d_in[3];
    const float* win1  = (const float*)d_in[4];
    const float* pyr2  = (const float*)d_in[5];
    const float* win2  = (const float*)d_in[6];
    const float* pyr3  = (const float*)d_in[7];
    const float* win3  = (const float*)d_in[8];
    float* ws  = (float*)d_ws;
    float* out = (float*)d_out;

    hipMemsetAsync(d_ws, 0, WS_FLOATS * sizeof(float), stream);
    pool_kernel<<<510, THREADS, 0, stream>>>(image, pyr0, win0, pyr1, win1,
                                             pyr2, win2, pyr3, win3, ws);
    finalize_kernel<<<(5100 + THREADS - 1) / THREADS, THREADS, 0, stream>>>(ws, out);
}

// Round 6
// 452.043 us; speedup vs baseline: 1.2522x; 1.1183x over previous
//
#include <hip/hip_runtime.h>

// VentralModel: log-polar Gaussian pooling over steerable-pyramid moduli.
// Output: 4 scales x (4 ori x 300 win) + 300 mean_lum = 5100 fp32.
//
// R6: exploit the enforced sparsity (reference: w[w<1e-6]=0). Windows are
// compact log-polar Gaussian blobs; only ~11-15% of window pixels are
// nonzero. Per (64x32 tile, window) we prove all-zero analytically:
//   window value = exp(-0.5*((dth/sa)^2 + (dlr/se)^2))  (float64 in ref)
//   skip iff min over tile's (theta, logr) rectangle of
//   (dth/sa)^2+(dlr/se)^2 > 27.8   [27.631 = 2*ln(1e6); margin => value
//   < 9.2e-7 < 1e-6 => stored as exact 0 => contributes nothing to sums,
//   count, or mean_lum]. Conservative: borderline tiles are still read.
// Keeps R5's proven folded 14-shuffle reduction + depth-2 nontemporal
// prefetch, now over a per-block alive-list built with one ballot.

#define THREADS 256
#define WPG 50                 // windows per group (6 groups x 50 = 300)
#define ZTHRESH 1e-20f

// ws float layout:
//   [0,4800)    sums[s][o][w]  (s*1200 + o*300 + w)
//   [4800,6000) cnt[s][w]      (4800 + s*300 + w)
//   [6000,6300) imgsum[w]
#define WS_FLOATS 6300

typedef float fvec4 __attribute__((ext_vector_type(4)));

__device__ __forceinline__ float rdist(float v, float a, float b) {
    return fmaxf(fmaxf(a - v, v - b), 0.f);   // distance from v to [a,b]
}

template <bool HAS_IMG>
__device__ __forceinline__ void pool_tile(const float* __restrict__ pyr,
                                          const float* __restrict__ win,
                                          const float* __restrict__ img,
                                          float* __restrict__ ws,
                                          int res, int scale, int x0, int y0, int wgrp)
{
    __shared__ float lacc[4][WPG * 6];
    __shared__ int s_list[WPG];
    __shared__ int s_na;

    const int tid  = threadIdx.x;
    const int lane = tid & 63;
    const int wave = tid >> 6;
    const int HW = res * res;
    const int w0 = wgrp * WPG;

    // ---- tile bounds + alive list (wave 0 only; one ballot) ----
    if (tid < 64) {
        float xlo = (float)x0 - res * 0.5f + 0.5f, xhi = xlo + 63.f;  // pixel centers
        float ylo = (float)y0 - res * 0.5f + 0.5f, yhi = ylo + 31.f;
        float dpp = 30.f / (float)res;            // MAX_ECC/(res/2)
        float dx = fmaxf(fmaxf(xlo, -xhi), 0.f);
        float dy = fmaxf(fmaxf(ylo, -yhi), 0.f);
        float rmin = sqrtf(dx * dx + dy * dy) * dpp;
        float rmax = sqrtf(fmaxf(xlo * xlo, xhi * xhi) + fmaxf(ylo * ylo, yhi * yhi)) * dpp;
        float lrmin = logf(fmaxf(rmin, 1e-6f));
        float lrmax = logf(fmaxf(rmax, 1e-6f));
        // theta range from corners; -x branch cut handled by wrap flag
        bool wrap = (ylo < 0.f && yhi > 0.f && xlo < 0.f);
        float t1 = atan2f(ylo, xlo), t2 = atan2f(ylo, xhi);
        float t3 = atan2f(yhi, xlo), t4 = atan2f(yhi, xhi);
        float tmin = fminf(fminf(t1, t2), fminf(t3, t4));
        float tmax = fmaxf(fmaxf(t1, t2), fmaxf(t3, t4));

        bool alive = false;
        if (lane < WPG) {
            int gw = w0 + lane;
            int e = gw / 20, p = gw - e * 20;
            float mue = -0.69314718f + (float)e * 0.24294267f;  // log(.5)+e*se
            float mua = -3.14159265f + (float)p * 0.31415927f;  // -pi+p*sa
            float dr = rdist(mue, lrmin, lrmax);
            float da = 0.f;
            if (!wrap) {
                float d0 = rdist(mua, tmin, tmax);
                float dm = rdist(mua - 6.2831853f, tmin, tmax);
                float dp = rdist(mua + 6.2831853f, tmin, tmax);
                da = fminf(d0, fminf(dm, dp));
            }
            float qa = da * 3.1830989f;   // /sa
            float qr = dr * 4.1161885f;   // /se
            alive = (qa * qa + qr * qr) <= 27.8f;   // 27.631 + margin
        }
        unsigned long long mask = __ballot(alive);
        if (alive) {
            int pos = (int)__popcll(mask & ((1ull << lane) - 1ull));
            s_list[pos] = lane;
        }
        if (lane == 0) s_na = (int)__popcll(mask);
    }
    __syncthreads();
    const int na = s_na;
    if (na == 0) return;   // uniform exit, no further barriers crossed

    // ---- per-thread pixels: 2 lane-contiguous float4 rows (rowA, rowA+16) ----
    const int row = tid >> 4;            // 0..15
    const int col = (tid & 15) * 4;      // 0..60
    const size_t p0 = (size_t)(y0 + row) * res + x0 + col;
    const size_t p1 = p0 + (size_t)16 * res;

    // moduli m0[o][j] (rowA), m1[o][j] (rowB)
    float m0[4][4], m1[4][4];
#pragma unroll
    for (int o = 0; o < 4; ++o) {
        const float4* pa = (const float4*)(pyr + ((size_t)o * HW + p0) * 2);
        float4 v0 = pa[0], v1 = pa[1];
        m0[o][0] = sqrtf(fmaf(v0.x, v0.x, v0.y * v0.y));
        m0[o][1] = sqrtf(fmaf(v0.z, v0.z, v0.w * v0.w));
        m0[o][2] = sqrtf(fmaf(v1.x, v1.x, v1.y * v1.y));
        m0[o][3] = sqrtf(fmaf(v1.z, v1.z, v1.w * v1.w));
        const float4* pb = (const float4*)(pyr + ((size_t)o * HW + p1) * 2);
        float4 w0v = pb[0], w1v = pb[1];
        m1[o][0] = sqrtf(fmaf(w0v.x, w0v.x, w0v.y * w0v.y));
        m1[o][1] = sqrtf(fmaf(w0v.z, w0v.z, w0v.w * w0v.w));
        m1[o][2] = sqrtf(fmaf(w1v.x, w1v.x, w1v.y * w1v.y));
        m1[o][3] = sqrtf(fmaf(w1v.z, w1v.z, w1v.w * w1v.w));
    }
    fvec4 i0 = (fvec4)(0.f), i1 = (fvec4)(0.f);
    if (HAS_IMG) {
        i0 = *(const fvec4*)(img + p0);
        i1 = *(const fvec4*)(img + p1);
    }

    const bool pb0 = (lane & 1) != 0;
    const bool pb1 = (lane & 2) != 0;
    const bool pb2 = (lane & 4) != 0;

    // ---- stream ALIVE windows, depth-2 nontemporal prefetch ----
    fvec4 x0v = (fvec4)(0.f), y0v = (fvec4)(0.f);
    fvec4 x1v = (fvec4)(0.f), y1v = (fvec4)(0.f);
    {
        const float* r0 = win + (size_t)(w0 + s_list[0]) * HW;
        x0v = __builtin_nontemporal_load((const fvec4*)(r0 + p0));
        y0v = __builtin_nontemporal_load((const fvec4*)(r0 + p1));
        if (na > 1) {
            const float* r1 = win + (size_t)(w0 + s_list[1]) * HW;
            x1v = __builtin_nontemporal_load((const fvec4*)(r1 + p0));
            y1v = __builtin_nontemporal_load((const fvec4*)(r1 + p1));
        }
    }

    for (int j = 0; j < na; ++j) {
        fvec4 xn = (fvec4)(0.f), yn = (fvec4)(0.f);
        if (j + 2 < na) {
            const float* r = win + (size_t)(w0 + s_list[j + 2]) * HW;
            xn = __builtin_nontemporal_load((const fvec4*)(r + p0));
            yn = __builtin_nontemporal_load((const fvec4*)(r + p1));
        }

        float a0 = 0.f, a1 = 0.f, a2 = 0.f, a3 = 0.f, ct = 0.f, ia = 0.f;
#pragma unroll
        for (int q = 0; q < 4; ++q) {
            float wx = x0v[q], wy = y0v[q];
            a0 = fmaf(wy, m1[0][q], fmaf(wx, m0[0][q], a0));
            a1 = fmaf(wy, m1[1][q], fmaf(wx, m0[1][q], a1));
            a2 = fmaf(wy, m1[2][q], fmaf(wx, m0[2][q], a2));
            a3 = fmaf(wy, m1[3][q], fmaf(wx, m0[3][q], a3));
            ct += (wx > ZTHRESH) ? 1.f : 0.f;
            ct += (wy > ZTHRESH) ? 1.f : 0.f;
            if (HAS_IMG) ia = fmaf(wy, i1[q], fmaf(wx, i0[q], ia));
        }

        // folded wave-64 reduction: all shuffles unconditional (R5-proven)
        float t0 = __shfl_xor(a0, 1, 64);
        float t1 = __shfl_xor(a1, 1, 64);
        float t2 = __shfl_xor(a2, 1, 64);
        float t3 = __shfl_xor(a3, 1, 64);
        float t4 = __shfl_xor(ct, 1, 64);
        float t5 = __shfl_xor(ia, 1, 64);
        float b0 = pb0 ? (a1 + t1) : (a0 + t0);
        float b1 = pb0 ? (a3 + t3) : (a2 + t2);
        float b2 = pb0 ? (ia + t5) : (ct + t4);
        float u0 = __shfl_xor(b0, 2, 64);
        float u1 = __shfl_xor(b1, 2, 64);
        float u2 = __shfl_xor(b2, 2, 64);
        float c0 = pb1 ? (b1 + u1) : (b0 + u0);
        float c1 = b2 + u2;
        float v0 = __shfl_xor(c0, 4, 64);
        float v1 = __shfl_xor(c1, 4, 64);
        float d  = pb2 ? (c1 + v1) : (c0 + v0);
        d += __shfl_xor(d, 8, 64);
        d += __shfl_xor(d, 16, 64);
        d += __shfl_xor(d, 32, 64);
        if (lane < 6) lacc[wave][j * 6 + lane] = d;

        x0v = x1v; y0v = y1v; x1v = xn; y1v = yn;
    }
    __syncthreads();

    // ---- block flush ----
    float* sums = ws + (size_t)scale * 1200;
    float* cnt  = ws + 4800 + (size_t)scale * 300;
    float* imgs = ws + 6000;
    for (int i = tid; i < na * 6; i += THREADS) {
        float v = lacc[0][i] + lacc[1][i] + lacc[2][i] + lacc[3][i];
        int j = i / 6, f = i - j * 6;
        int w = w0 + s_list[j];
        if (f < 4) {
            atomicAdd(&sums[f * 300 + w], v);
        } else if (f == 4) {
            atomicAdd(&cnt[w], v);
        } else if (HAS_IMG) {
            atomicAdd(&imgs[w], v);
        }
    }
}

// grid: s0: 128 tiles x 6 grps = 768 | s1: 32x6=192 | s2: 8x6=48 | s3: 2x6=12
// total 1020 blocks; tiles are 64x32 px at every scale.
__global__ __launch_bounds__(THREADS)
void pool_kernel(const float* __restrict__ image,
                 const float* __restrict__ pyr0, const float* __restrict__ win0,
                 const float* __restrict__ pyr1, const float* __restrict__ win1,
                 const float* __restrict__ pyr2, const float* __restrict__ win2,
                 const float* __restrict__ pyr3, const float* __restrict__ win3,
                 float* __restrict__ ws)
{
    int bid = blockIdx.x;
    if (bid < 768) {
        int wgrp = bid >> 7, tile = bid & 127;
        int tx = tile & 7, ty = tile >> 3;           // 8 x 16 tiles
        pool_tile<true>(pyr0, win0, image, ws, 512, 0, tx * 64, ty * 32, wgrp);
    } else if (bid < 960) {
        int l = bid - 768;
        int wgrp = l >> 5, tile = l & 31;
        int tx = tile & 3, ty = tile >> 2;           // 4 x 8
        pool_tile<false>(pyr1, win1, nullptr, ws, 256, 1, tx * 64, ty * 32, wgrp);
    } else if (bid < 1008) {
        int l = bid - 960;
        int wgrp = l >> 3, tile = l & 7;
        int tx = tile & 1, ty = tile >> 1;           // 2 x 4
        pool_tile<false>(pyr2, win2, nullptr, ws, 128, 2, tx * 64, ty * 32, wgrp);
    } else {
        int l = bid - 1008;
        int wgrp = l >> 1, tile = l & 1;             // 1 x 2
        pool_tile<false>(pyr3, win3, nullptr, ws, 64, 3, 0, tile * 32, wgrp);
    }
}

__global__ __launch_bounds__(THREADS)
void finalize_kernel(const float* __restrict__ ws, float* __restrict__ out)
{
    int i = blockIdx.x * blockDim.x + threadIdx.x;
    if (i >= 5100) return;
    float v;
    if (i < 4800) {
        int s = i / 1200;
        int w = i % 300;
        v = ws[i] / ws[4800 + s * 300 + w];        // sums[s][o][w] / cnt[s][w]
    } else {
        int w = i - 4800;
        v = ws[6000 + w] / ws[4800 + w];           // imgsum[w] / cnt[0][w]
    }
    out[i] = v;
}

extern "C" void kernel_launch(void* const* d_in, const int* in_sizes, int n_in,
                              void* d_out, int out_size, void* d_ws, size_t ws_size,
                              hipStream_t stream)
{
    const float* image = (const float*)d_in[0];
    const float* pyr0  = (const float*)d_in[1];
    const float* win0  = (const float*)d_in[2];
    const float* pyr1  = (const float*)d_in[3];
    const float* win1  = (const float*)d_in[4];
    const float* pyr2  = (const float*)d_in[5];
    const float* win2  = (const float*)d_in[6];
    const float* pyr3  = (const float*)d_in[7];
    const float* win3  = (const float*)d_in[8];
    float* ws  = (float*)d_ws;
    float* out = (float*)d_out;

    hipMemsetAsync(d_ws, 0, WS_FLOATS * sizeof(float), stream);
    pool_kernel<<<1020, THREADS, 0, stream>>>(image, pyr0, win0, pyr1, win1,
                                              pyr2, win2, pyr3, win3, ws);
    finalize_kernel<<<(5100 + THREADS - 1) / THREADS, THREADS, 0, stream>>>(ws, out);
}